// Round 1
// baseline (5004.345 us; speedup 1.0000x reference)
//
#include <hip/hip_runtime.h>
#include <hip/hip_bf16.h>

#define N_TOK   8192
#define DM      1024     // d_model
#define DH      16384    // d_hidden
#define KTOP    32

// ---------------------------------------------------------------------------
// Encode GEMM: pre[n][h] = sum_d (x[n][d] - b_pre[d]) * W_enc[h][d] + b_act[h]
// A = x [N, DM] row-major, B = W_enc [DH, DM] row-major  (NT layout, both
// contiguous along k=d). Tile 64x64, BK=32, 4x4 microtile, 256 threads.
// LDS tiles stored transposed [k][m] so fragment reads are ds_read_b128.
// ---------------------------------------------------------------------------
__global__ __launch_bounds__(256) void gemm_enc(
    const float* __restrict__ x, const float* __restrict__ W,
    const float* __restrict__ b_pre, const float* __restrict__ b_act,
    float* __restrict__ pre)
{
    const int BK = 32;
    __shared__ float As[32][68];   // [k][m], pad 68: rows 272B (16B-aligned), write 2-way max
    __shared__ float Bs[32][68];

    const int tid = threadIdx.x;
    const int tx = tid & 15;    // h micro index
    const int ty = tid >> 4;    // n micro index
    const int n0 = blockIdx.y * 64;
    const int h0 = blockIdx.x * 64;

    float acc[4][4];
    #pragma unroll
    for (int i = 0; i < 4; ++i)
        #pragma unroll
        for (int j = 0; j < 4; ++j) acc[i][j] = 0.f;

    for (int k0 = 0; k0 < DM; k0 += BK) {
        // cooperative load: 64 rows x 32 k each for A and B (2048 elems each)
        #pragma unroll
        for (int r = 0; r < 8; ++r) {
            int idx = tid + r * 256;
            int row = idx >> 5;      // 0..63
            int kk  = idx & 31;
            As[kk][row] = x[(size_t)(n0 + row) * DM + k0 + kk] - b_pre[k0 + kk];
            Bs[kk][row] = W[(size_t)(h0 + row) * DM + k0 + kk];
        }
        __syncthreads();
        #pragma unroll
        for (int kk = 0; kk < BK; ++kk) {
            float4 a4 = *(const float4*)&As[kk][ty * 4];
            float4 b4 = *(const float4*)&Bs[kk][tx * 4];
            float a[4] = {a4.x, a4.y, a4.z, a4.w};
            float b[4] = {b4.x, b4.y, b4.z, b4.w};
            #pragma unroll
            for (int i = 0; i < 4; ++i)
                #pragma unroll
                for (int j = 0; j < 4; ++j)
                    acc[i][j] = fmaf(a[i], b[j], acc[i][j]);
        }
        __syncthreads();
    }

    float4 ba = *(const float4*)&b_act[h0 + tx * 4];
    float bav[4] = {ba.x, ba.y, ba.z, ba.w};
    #pragma unroll
    for (int i = 0; i < 4; ++i) {
        int n = n0 + ty * 4 + i;
        float4 o;
        o.x = acc[i][0] + bav[0];
        o.y = acc[i][1] + bav[1];
        o.z = acc[i][2] + bav[2];
        o.w = acc[i][3] + bav[3];
        *(float4*)&pre[(size_t)n * DH + h0 + tx * 4] = o;
    }
}

// ---------------------------------------------------------------------------
// Per-row top-32. One block (512 threads) per row; each thread caches 32
// values in registers. Iterative argmax with incremental local-max
// maintenance: block reduce picks the winner; only the owning thread
// invalidates and rescans its 32 registers. Tie-break: lower global index
// (matches jax.lax.top_k stability).
// ---------------------------------------------------------------------------
__global__ __launch_bounds__(512) void topk_kernel(
    const float* __restrict__ pre, float* __restrict__ sparse,
    float* __restrict__ vals, int* __restrict__ inds)
{
    const int row = blockIdx.x;
    const int tid = threadIdx.x;
    const float NEG = -__builtin_inff();

    const float* __restrict__ p = pre + (size_t)row * DH;
    float v[32];
    #pragma unroll
    for (int j = 0; j < 32; ++j) v[j] = p[j * 512 + tid];

    // local argmax over the 32 cached values (global index = j*512 + tid)
    float lv = v[0]; int lj = 0;
    #pragma unroll
    for (int j = 1; j < 32; ++j) { if (v[j] > lv) { lv = v[j]; lj = j; } }

    __shared__ float sv[8];
    __shared__ int   si[8];
    __shared__ float wv;
    __shared__ int   wi;

    for (int it = 0; it < KTOP; ++it) {
        float rv = lv;
        int   ri = lj * 512 + tid;
        #pragma unroll
        for (int off = 32; off; off >>= 1) {
            float ov = __shfl_down(rv, off);
            int   oi = __shfl_down(ri, off);
            if (ov > rv || (ov == rv && oi < ri)) { rv = ov; ri = oi; }
        }
        if ((tid & 63) == 0) { sv[tid >> 6] = rv; si[tid >> 6] = ri; }
        __syncthreads();
        if (tid == 0) {
            float bv = sv[0]; int bi = si[0];
            #pragma unroll
            for (int w = 1; w < 8; ++w) {
                if (sv[w] > bv || (sv[w] == bv && si[w] < bi)) { bv = sv[w]; bi = si[w]; }
            }
            wv = bv; wi = bi;
            float rl = bv > 0.f ? bv : 0.f;
            vals[row * KTOP + it] = rl;            // stored post-relu
            inds[row * KTOP + it] = bi;
            sparse[(size_t)row * DH + bi] = rl;
        }
        __syncthreads();
        int bwi = wi;
        if ((bwi & 511) == tid) {
            int jw = bwi >> 9;
            #pragma unroll
            for (int j = 0; j < 32; ++j) if (j == jw) v[j] = NEG;
            lv = v[0]; lj = 0;
            #pragma unroll
            for (int j = 1; j < 32; ++j) { if (v[j] > lv) { lv = v[j]; lj = j; } }
        }
        __syncthreads();
    }
}

// ---------------------------------------------------------------------------
// Transpose W_dec [DM, DH] -> W_dec^T [DH, DM]
// ---------------------------------------------------------------------------
__global__ __launch_bounds__(256) void transpose_kernel(
    const float* __restrict__ W, float* __restrict__ WT)
{
    __shared__ float t[32][33];
    const int tx = threadIdx.x;   // 0..31
    const int ty = threadIdx.y;   // 0..7
    const int h0 = blockIdx.x * 32;
    const int d0 = blockIdx.y * 32;
    #pragma unroll
    for (int r = 0; r < 4; ++r) {
        int d = d0 + ty + r * 8;
        t[ty + r * 8][tx] = W[(size_t)d * DH + h0 + tx];
    }
    __syncthreads();
    #pragma unroll
    for (int r = 0; r < 4; ++r) {
        int h = h0 + ty + r * 8;
        WT[(size_t)h * DM + d0 + tx] = t[tx][ty + r * 8];
    }
}

// ---------------------------------------------------------------------------
// Decode: recon[n][d] = sum_j vals[n][j] * WdecT[inds[n][j]][d] + b_pre[d]
// One block per row, 256 threads, float4 per thread. WdecT rows contiguous
// (coalesced); 67MB table is L3-resident. Fallback path reads W_dec strided.
// ---------------------------------------------------------------------------
__global__ __launch_bounds__(256) void recon_kernel(
    const float* __restrict__ vals, const int* __restrict__ inds,
    const float* __restrict__ wdecT, const float* __restrict__ W_dec,
    const float* __restrict__ b_pre, float* __restrict__ recon, int useT)
{
    const int row = blockIdx.x;
    const int tid = threadIdx.x;
    __shared__ float lval[KTOP];
    __shared__ int   lind[KTOP];
    if (tid < KTOP) { lval[tid] = vals[row * KTOP + tid]; lind[tid] = inds[row * KTOP + tid]; }
    __syncthreads();

    const int d = tid * 4;
    float4 a = *(const float4*)&b_pre[d];
    if (useT) {
        #pragma unroll 8
        for (int j = 0; j < KTOP; ++j) {
            float vj = lval[j];
            if (vj != 0.f) {   // uniform branch (LDS value, same for all threads)
                const float4 w = *(const float4*)&wdecT[(size_t)lind[j] * DM + d];
                a.x = fmaf(vj, w.x, a.x);
                a.y = fmaf(vj, w.y, a.y);
                a.z = fmaf(vj, w.z, a.z);
                a.w = fmaf(vj, w.w, a.w);
            }
        }
    } else {
        for (int j = 0; j < KTOP; ++j) {
            float vj = lval[j];
            if (vj != 0.f) {
                int h = lind[j];
                a.x = fmaf(vj, W_dec[(size_t)(d + 0) * DH + h], a.x);
                a.y = fmaf(vj, W_dec[(size_t)(d + 1) * DH + h], a.y);
                a.z = fmaf(vj, W_dec[(size_t)(d + 2) * DH + h], a.z);
                a.w = fmaf(vj, W_dec[(size_t)(d + 3) * DH + h], a.w);
            }
        }
    }
    *(float4*)&recon[(size_t)row * DM + d] = a;
}

// ---------------------------------------------------------------------------
extern "C" void kernel_launch(void* const* d_in, const int* in_sizes, int n_in,
                              void* d_out, int out_size, void* d_ws, size_t ws_size,
                              hipStream_t stream)
{
    const float* x     = (const float*)d_in[0];
    const float* W_enc = (const float*)d_in[1];
    const float* W_dec = (const float*)d_in[2];
    const float* b_pre = (const float*)d_in[3];
    const float* b_act = (const float*)d_in[4];

    float* recon  = (float*)d_out;                       // [N, DM]
    float* sparse = recon + (size_t)N_TOK * DM;          // [N, DH]
    float* pre    = sparse + (size_t)N_TOK * DH;         // [N, DH]

    const size_t wT_elems = (size_t)DH * DM;
    const size_t needT = wT_elems * sizeof(float)
                       + (size_t)N_TOK * KTOP * (sizeof(float) + sizeof(int));
    const int useT = ws_size >= needT;

    float* wdecT; float* vals; int* inds;
    if (useT) {
        wdecT = (float*)d_ws;
        vals  = wdecT + wT_elems;
        inds  = (int*)(vals + (size_t)N_TOK * KTOP);
    } else {
        wdecT = (float*)d_ws;  // unused
        vals  = (float*)d_ws;
        inds  = (int*)(vals + (size_t)N_TOK * KTOP);
    }

    // zero the sparse_acts region (scatter only writes 32 per row)
    hipMemsetAsync(sparse, 0, (size_t)N_TOK * DH * sizeof(float), stream);

    // encode GEMM
    dim3 ggrid(DH / 64, N_TOK / 64);
    gemm_enc<<<ggrid, 256, 0, stream>>>(x, W_enc, b_pre, b_act, pre);

    // transpose W_dec (independent of GEMM, stream-ordered anyway)
    if (useT) {
        dim3 tgrid(DH / 32, DM / 32);
        transpose_kernel<<<tgrid, dim3(32, 8), 0, stream>>>(W_dec, wdecT);
    }

    // top-k per row
    topk_kernel<<<N_TOK, 512, 0, stream>>>(pre, sparse, vals, inds);

    // decode
    recon_kernel<<<N_TOK, 256, 0, stream>>>(vals, inds, wdecT, W_dec, b_pre, recon, useT);
}

// Round 2
// 910.664 us; speedup vs baseline: 5.4953x; 5.4953x over previous
//
#include <hip/hip_runtime.h>
#include <hip/hip_bf16.h>

#define N_TOK   8192
#define DM      1024     // d_model
#define DH      16384    // d_hidden
#define KTOP    32
#define NCAND   256      // candidate buffer per row

typedef unsigned int uint;
typedef __attribute__((ext_vector_type(8))) short bf16x8;
typedef __attribute__((ext_vector_type(4))) float f32x4;

__device__ inline ushort f2bf(float f) {
    uint u = __float_as_uint(f);
    uint r = (u + 0x7FFFu + ((u >> 16) & 1u)) >> 16;
    return (ushort)r;
}
__device__ inline float bf2f(ushort u) {
    return __uint_as_float(((uint)u) << 16);
}

__device__ inline void load_lds16(const void* g, void* l) {
    __builtin_amdgcn_global_load_lds(
        (const __attribute__((address_space(1))) void*)g,
        (__attribute__((address_space(3))) void*)l, 16, 0, 0);
}

// ---------------------------------------------------------------------------
// Convert x -> bf16(x - b_pre)   [N_TOK, DM]
// ---------------------------------------------------------------------------
__global__ __launch_bounds__(256) void conv_x(
    const float* __restrict__ x, const float* __restrict__ b_pre,
    ushort* __restrict__ A)
{
    int i = (blockIdx.x * 256 + threadIdx.x) * 4;
    float4 v = *(const float4*)&x[i];
    float4 b = *(const float4*)&b_pre[i & (DM - 1)];
    ushort4 o;
    o.x = f2bf(v.x - b.x); o.y = f2bf(v.y - b.y);
    o.z = f2bf(v.z - b.z); o.w = f2bf(v.w - b.w);
    *(ushort4*)&A[i] = o;
}

// Convert W_enc -> bf16   [DH, DM]
__global__ __launch_bounds__(256) void conv_w(
    const float* __restrict__ W, ushort* __restrict__ B)
{
    int i = (blockIdx.x * 256 + threadIdx.x) * 4;
    float4 v = *(const float4*)&W[i];
    ushort4 o;
    o.x = f2bf(v.x); o.y = f2bf(v.y); o.z = f2bf(v.z); o.w = f2bf(v.w);
    *(ushort4*)&B[i] = o;
}

// ---------------------------------------------------------------------------
// bf16 MFMA GEMM (m97 structure): pre[n][h] = A[n][:] . B[h][:] + b_act[h]
// A [N_TOK, DM] bf16 row-major, B [DH, DM] bf16 row-major (NT).
// BM=BN=128, BK=64, 256 threads (4 waves, 2x2), each wave 64x64 out
// (4x4 frags of 16x16x32). global_load_lds width-16 staging, linear LDS.
// ---------------------------------------------------------------------------
__global__ __launch_bounds__(256, 3) void gemm_bf16(
    const ushort* __restrict__ A, const ushort* __restrict__ B,
    const float* __restrict__ b_act, float* __restrict__ pre)
{
    __shared__ ushort As[128 * 64];   // 16 KB
    __shared__ ushort Bs[128 * 64];   // 16 KB

    const int tid  = threadIdx.x;
    const int wid  = tid >> 6;
    const int lane = tid & 63;
    const int wr   = wid >> 1;        // wave row 0..1
    const int wc   = wid & 1;         // wave col 0..1

    // XCD-aware bijective swizzle (8192 % 8 == 0), bn-major for L2 B reuse
    int swz = (blockIdx.x & 7) * 1024 + (blockIdx.x >> 3);
    const int bm = swz & 63;          // 64 row tiles
    const int bn = swz >> 6;          // 128 col tiles
    const int row0 = bm * 128;
    const int col0 = bn * 128;

    f32x4 acc[4][4] = {};

    // staging: tile = 128 rows x 64 bf16 = 1024 chunks of 16B
    const int chunk = wid * 64 + lane;          // within a 256-chunk instr
    for (int k0 = 0; k0 < DM; k0 += 64) {
        #pragma unroll
        for (int i = 0; i < 4; ++i) {
            int ch = i * 256 + chunk;
            int r  = ch >> 3;
            int c8 = (ch & 7) * 8;
            load_lds16(&A[(size_t)(row0 + r) * DM + k0 + c8],
                       &As[(size_t)(i * 256 + wid * 64) * 8]);
            load_lds16(&B[(size_t)(col0 + r) * DM + k0 + c8],
                       &Bs[(size_t)(i * 256 + wid * 64) * 8]);
        }
        __syncthreads();
        #pragma unroll
        for (int ks = 0; ks < 2; ++ks) {
            const int kb = ks * 32 + (lane >> 4) * 8;   // ushort offset in row
            bf16x8 af[4], bfr[4];
            #pragma unroll
            for (int m = 0; m < 4; ++m)
                af[m] = *(const bf16x8*)&As[(wr * 64 + m * 16 + (lane & 15)) * 64 + kb];
            #pragma unroll
            for (int n = 0; n < 4; ++n)
                bfr[n] = *(const bf16x8*)&Bs[(wc * 64 + n * 16 + (lane & 15)) * 64 + kb];
            #pragma unroll
            for (int m = 0; m < 4; ++m)
                #pragma unroll
                for (int n = 0; n < 4; ++n)
                    acc[m][n] = __builtin_amdgcn_mfma_f32_16x16x32_bf16(
                        af[m], bfr[n], acc[m][n], 0, 0, 0);
        }
        __syncthreads();
    }

    // epilogue: C row = (lane>>4)*4 + r within frag, col = lane&15
    const int ccol = col0 + wc * 64 + (lane & 15);
    float ba[4];
    #pragma unroll
    for (int n = 0; n < 4; ++n) ba[n] = b_act[ccol + n * 16];
    #pragma unroll
    for (int m = 0; m < 4; ++m) {
        const int crow = row0 + wr * 64 + m * 16 + (lane >> 4) * 4;
        #pragma unroll
        for (int r = 0; r < 4; ++r) {
            #pragma unroll
            for (int n = 0; n < 4; ++n)
                pre[(size_t)(crow + r) * DH + ccol + n * 16] = acc[m][n][r] + ba[n];
        }
    }
}

// ---------------------------------------------------------------------------
// Candidate extraction: per row, find threshold t with count(>t) in [96,250]
// (bisection over register-cached values), compact candidates to ws.
// Also zeroes the sparse_acts row.
// ---------------------------------------------------------------------------
__global__ __launch_bounds__(512) void topk_cand(
    const float* __restrict__ pre, float* __restrict__ sparse,
    float* __restrict__ cval, int* __restrict__ cidx, int* __restrict__ ccnt)
{
    const int row = blockIdx.x;
    const int tid = threadIdx.x;
    const float* __restrict__ p = pre + (size_t)row * DH;

    float v[32];
    #pragma unroll
    for (int j = 0; j < 32; ++j) v[j] = p[j * 512 + tid];

    // zero sparse row (4096 float4)
    float4 z = {0.f, 0.f, 0.f, 0.f};
    float4* srow = (float4*)(sparse + (size_t)row * DH);
    #pragma unroll
    for (int i = 0; i < 8; ++i) srow[tid + i * 512] = z;

    __shared__ int scount;
    float lo = -30.f, hi = 30.f, t = 0.f;
    for (int it = 0; it < 20; ++it) {
        t = 0.5f * (lo + hi);
        int c = 0;
        #pragma unroll
        for (int j = 0; j < 32; ++j) c += (v[j] > t);
        #pragma unroll
        for (int off = 32; off; off >>= 1) c += __shfl_down(c, off);
        if (tid == 0) scount = 0;
        __syncthreads();
        if ((tid & 63) == 0) atomicAdd(&scount, c);
        __syncthreads();
        int total = scount;
        __syncthreads();
        if (total >= 96 && total <= 250) break;
        if (total < 96) hi = t; else lo = t;
    }

    __shared__ int wpos;
    __shared__ float scv[NCAND];
    __shared__ int   sci[NCAND];
    if (tid == 0) wpos = 0;
    __syncthreads();
    #pragma unroll
    for (int j = 0; j < 32; ++j) {
        if (v[j] > t) {
            int pz = atomicAdd(&wpos, 1);
            if (pz < NCAND) { scv[pz] = v[j]; sci[pz] = j * 512 + tid; }
        }
    }
    __syncthreads();
    int n = min(wpos, NCAND);
    if (tid == 0) ccnt[row] = n;
    if (tid < NCAND) {
        cval[(size_t)row * NCAND + tid] = (tid < n) ? scv[tid] : -1e30f;
        cidx[(size_t)row * NCAND + tid] = (tid < n) ? sci[tid] : -1;
    }
}

// ---------------------------------------------------------------------------
// Exact top-32: sort 256 candidates (desc, idx-asc tiebreak), exact f32
// recompute of candidates within +-2*delta of approx 32nd value, re-rank,
// write vals/inds + scatter into sparse.
// ---------------------------------------------------------------------------
__device__ inline void bitonic256(float* key, float* val, int* idx, int tid)
{
    for (int k = 2; k <= 256; k <<= 1) {
        for (int j = k >> 1; j; j >>= 1) {
            int ixj = tid ^ j;
            if (ixj > tid) {
                float ka = key[tid], kb = key[ixj];
                int ia = idx[tid], ib = idx[ixj];
                bool a_first = (ka > kb) || (ka == kb && ia < ib); // rank order
                bool desc = ((tid & k) == 0);
                if (desc != a_first) {
                    key[tid] = kb; key[ixj] = ka;
                    float va = val[tid]; val[tid] = val[ixj]; val[ixj] = va;
                    idx[tid] = ib; idx[ixj] = ia;
                }
            }
            __syncthreads();
        }
    }
}

__global__ __launch_bounds__(256) void fix_topk(
    const float* __restrict__ x, const float* __restrict__ b_pre,
    const float* __restrict__ W, const float* __restrict__ b_act,
    const float* __restrict__ cval, const int* __restrict__ cidx,
    float* __restrict__ sparse, float* __restrict__ vals, int* __restrict__ inds)
{
    const int row = blockIdx.x;
    const int tid = threadIdx.x;
    const int wid = tid >> 6, lane = tid & 63;

    __shared__ float xs[DM];
    for (int i = tid; i < DM; i += 256)
        xs[i] = x[(size_t)row * DM + i] - b_pre[i];

    __shared__ float key[NCAND];
    __shared__ float val[NCAND];
    __shared__ int   idx[NCAND];
    key[tid] = cval[(size_t)row * NCAND + tid];
    val[tid] = key[tid];
    idx[tid] = cidx[(size_t)row * NCAND + tid];
    __syncthreads();

    bitonic256(key, val, idx, tid);

    const float DZ = 0.04f;   // 2 * delta (delta = bf16-GEMM error bound)
    float a32 = key[31];
    __shared__ int z0s, z1s;
    if (tid == 0) { z0s = 256; z1s = 256; }
    __syncthreads();
    if (key[tid] <= a32 + DZ) atomicMin(&z0s, tid);
    if (key[tid] <  a32 - DZ) atomicMin(&z1s, tid);
    __syncthreads();
    const int z0 = z0s, z1 = z1s;

    // exact f32 recompute of zone members (one per wave, round-robin)
    for (int m = z0 + wid; m < z1; m += 4) {
        int h = idx[m];
        if (h >= 0) {
            const float* wrow = W + (size_t)h * DM;
            float s = 0.f;
            #pragma unroll
            for (int c = 0; c < 16; ++c)
                s = fmaf(xs[lane + c * 64], wrow[lane + c * 64], s);
            #pragma unroll
            for (int off = 32; off; off >>= 1) s += __shfl_down(s, off);
            if (lane == 0) { float e = s + b_act[h]; key[m] = e; val[m] = e; }
        }
    }
    __syncthreads();

    // certain-in stays on top; certain-out deflated; zone ranked by exact val
    if (tid < z0)       key[tid] = 1e30f - (float)tid;
    else if (tid >= z1) key[tid] = -1e30f;
    __syncthreads();

    bitonic256(key, val, idx, tid);

    if (tid < KTOP) {
        float v = val[tid];
        int h = idx[tid];
        float r = v > 0.f ? v : 0.f;
        vals[(size_t)row * KTOP + tid] = r;
        inds[(size_t)row * KTOP + tid] = h;
        if (h >= 0) sparse[(size_t)row * DH + h] = r;
    }
}

// ---------------------------------------------------------------------------
// Transpose W_dec [DM, DH] f32 -> W_dec^T [DH, DM] bf16
// ---------------------------------------------------------------------------
__global__ __launch_bounds__(256) void transpose_dec(
    const float* __restrict__ W, ushort* __restrict__ WT)
{
    __shared__ float t[32][33];
    const int tx = threadIdx.x;   // 0..31
    const int ty = threadIdx.y;   // 0..7
    const int h0 = blockIdx.x * 32;
    const int d0 = blockIdx.y * 32;
    #pragma unroll
    for (int r = 0; r < 4; ++r)
        t[ty + r * 8][tx] = W[(size_t)(d0 + ty + r * 8) * DH + h0 + tx];
    __syncthreads();
    #pragma unroll
    for (int r = 0; r < 4; ++r)
        WT[(size_t)(h0 + ty + r * 8) * DM + d0 + tx] = f2bf(t[tx][ty + r * 8]);
}

// ---------------------------------------------------------------------------
// Decode: recon[n][d] = sum_j vals[n][j] * WdecT[inds[n][j]][d] + b_pre[d]
// ---------------------------------------------------------------------------
__global__ __launch_bounds__(256) void recon_kernel(
    const float* __restrict__ vals, const int* __restrict__ inds,
    const ushort* __restrict__ wdecT, const float* __restrict__ b_pre,
    float* __restrict__ recon)
{
    const int row = blockIdx.x;
    const int tid = threadIdx.x;
    __shared__ float lval[KTOP];
    __shared__ int   lind[KTOP];
    if (tid < KTOP) {
        lval[tid] = vals[(size_t)row * KTOP + tid];
        lind[tid] = inds[(size_t)row * KTOP + tid];
    }
    __syncthreads();

    const int d = tid * 4;
    float4 a = *(const float4*)&b_pre[d];
    #pragma unroll 8
    for (int j = 0; j < KTOP; ++j) {
        float vj = lval[j];
        int h = lind[j];
        if (vj != 0.f && h >= 0) {
            ushort4 w = *(const ushort4*)&wdecT[(size_t)h * DM + d];
            a.x = fmaf(vj, bf2f(w.x), a.x);
            a.y = fmaf(vj, bf2f(w.y), a.y);
            a.z = fmaf(vj, bf2f(w.z), a.z);
            a.w = fmaf(vj, bf2f(w.w), a.w);
        }
    }
    *(float4*)&recon[(size_t)row * DM + d] = a;
}

// ---------------------------------------------------------------------------
extern "C" void kernel_launch(void* const* d_in, const int* in_sizes, int n_in,
                              void* d_out, int out_size, void* d_ws, size_t ws_size,
                              hipStream_t stream)
{
    const float* x     = (const float*)d_in[0];
    const float* W_enc = (const float*)d_in[1];
    const float* W_dec = (const float*)d_in[2];
    const float* b_pre = (const float*)d_in[3];
    const float* b_act = (const float*)d_in[4];

    float* recon  = (float*)d_out;                       // [N, DM]
    float* sparse = recon + (size_t)N_TOK * DM;          // [N, DH]
    float* pre    = sparse + (size_t)N_TOK * DH;         // [N, DH]

    // bf16 staging of A/B inside the (later-zeroed) sparse output region
    ushort* Abf = (ushort*)sparse;                       // 16.8 MB
    ushort* Bbf = Abf + (size_t)N_TOK * DM;              // 33.5 MB

    // workspace layout (~52.5 MB)
    float*  cval  = (float*)d_ws;                               // 8.39 MB
    int*    cidx  = (int*)(cval + (size_t)N_TOK * NCAND);       // 8.39 MB
    int*    ccnt  = cidx + (size_t)N_TOK * NCAND;               // 32 KB
    float*  vals  = (float*)(ccnt + N_TOK);                     // 1.05 MB
    int*    inds  = (int*)(vals + (size_t)N_TOK * KTOP);        // 1.05 MB
    ushort* wdecT = (ushort*)(inds + (size_t)N_TOK * KTOP);     // 33.5 MB

    conv_x<<<N_TOK * DM / 1024, 256, 0, stream>>>(x, b_pre, Abf);
    conv_w<<<DH * DM / 1024, 256, 0, stream>>>(W_enc, Bbf);

    gemm_bf16<<<(N_TOK / 128) * (DH / 128), 256, 0, stream>>>(Abf, Bbf, b_act, pre);

    transpose_dec<<<dim3(DH / 32, DM / 32), dim3(32, 8), 0, stream>>>(W_dec, wdecT);

    topk_cand<<<N_TOK, 512, 0, stream>>>(pre, sparse, cval, cidx, ccnt);

    fix_topk<<<N_TOK, 256, 0, stream>>>(x, b_pre, W_enc, b_act,
                                        cval, cidx, sparse, vals, inds);

    recon_kernel<<<N_TOK, 256, 0, stream>>>(vals, inds, wdecT, b_pre, recon);
}